// Round 1
// baseline (390.429 us; speedup 1.0000x reference)
//
#include <hip/hip_runtime.h>
#include <hip/hip_bf16.h>

// DSMoE: B=4,S=2048 -> T=8192 tokens, D=512, H=1024, E=8 routed (top-2) + shared.
// bf16 MFMA token-gather MoE; shared expert folded in as expert 8.
// R7: stage1/stage2 ported to the 256x256 8-phase schedule (T3+T4 counted vmcnt,
//     T5 setprio, T2 swizzle kept): 512 thr / 8 waves, BK=64, 128KiB LDS ring of
//     8 half-tiles, vmcnt(4) checkpoints at phases 4/8 (vmcnt(0) on tail iter).

#define Tn 8192
#define Dd 512
#define Hh 1024
#define NEx 9

typedef __attribute__((ext_vector_type(8))) short short8;
typedef __attribute__((ext_vector_type(4))) float f32x4;

#define AS1 __attribute__((address_space(1)))
#define AS3 __attribute__((address_space(3)))

#define OFF_XB    ((size_t)0)
#define OFF_W13T  (OFF_XB + (size_t)Tn * Dd * 2)
#define OFF_W2T   (OFF_W13T + (size_t)NEx * 2 * Hh * Dd * 2)
#define OFF_HBUF  (OFF_W2T + (size_t)NEx * Dd * Hh * 2)
#define OFF_TOK   (OFF_HBUF + (size_t)(3 * Tn) * Hh * 2)
#define OFF_SLOTP (OFF_TOK + (size_t)8 * Tn * 4)
#define OFF_PG    (OFF_SLOTP + (size_t)Tn * 2 * 4)
#define OFF_CNT   (OFF_PG + (size_t)Tn * 2 * 4)       // 8 counters, 128B apart
#define OFF_OFFS  (OFF_CNT + 1024)                    // off[9] then cntc[9]
#define OFF_YC    OFF_XB   // alias: Yc (25.2MB) over xb+w13t (26.9MB), dead by stage2

__device__ __forceinline__ ushort f2bf(float f) {
    unsigned int u = __float_as_uint(f);
    return (ushort)((u + 0x7fffu + ((u >> 16) & 1u)) >> 16);
}
__device__ __forceinline__ float bf2f(short s) {
    return __uint_as_float(((unsigned int)(unsigned short)s) << 16);
}

// ---------- fused transpose: 27 slices; fam 0/1 interleave into w13t ----------
// fam 0: w1, fam 1: w3 -> w13t rows n = ((h>>4)*2+fam)*16 + (h&15); fam 2: w2 plain.
__global__ __launch_bounds__(256) void trans_kernel(
        const float* __restrict__ w1, const float* __restrict__ sw1,
        const float* __restrict__ w3, const float* __restrict__ sw3,
        const float* __restrict__ w2, const float* __restrict__ sw2,
        ushort* __restrict__ w13t, ushort* __restrict__ w2t) {
    __shared__ float tile[32][33];
    int z = blockIdx.z;
    int fam = z / 9, sl = z - fam * 9;
    int tx = threadIdx.x & 31, ty = threadIdx.x >> 5;
    if (fam < 2) {
        const float* base = (fam == 0) ? ((sl < 8) ? w1 + (size_t)sl * Dd * Hh : sw1)
                                       : ((sl < 8) ? w3 + (size_t)sl * Dd * Hh : sw3);
        ushort* dst = w13t + (size_t)sl * 2 * Hh * Dd;
        int c0 = blockIdx.x * 32, r0 = blockIdx.y * 32;   // c: hidden, r: dim
#pragma unroll
        for (int k = 0; k < 4; ++k)
            tile[ty + 8 * k][tx] = base[(size_t)(r0 + ty + 8 * k) * Hh + c0 + tx];
        __syncthreads();
#pragma unroll
        for (int k = 0; k < 4; ++k) {
            int h = c0 + ty + 8 * k;
            int n = (((h >> 4) * 2 + fam) << 4) + (h & 15);
            dst[(size_t)n * Dd + r0 + tx] = f2bf(tile[tx][ty + 8 * k]);
        }
    } else {
        const float* base = (sl < 8) ? w2 + (size_t)sl * Dd * Hh : sw2;
        ushort* dst = w2t + (size_t)sl * Dd * Hh;
        int r0 = blockIdx.x * 32, c0 = blockIdx.y * 32;   // r: hidden, c: dim
#pragma unroll
        for (int k = 0; k < 4; ++k)
            tile[ty + 8 * k][tx] = base[(size_t)(r0 + ty + 8 * k) * Dd + c0 + tx];
        __syncthreads();
#pragma unroll
        for (int k = 0; k < 4; ++k)
            dst[(size_t)(c0 + ty + 8 * k) * Hh + r0 + tx] = f2bf(tile[tx][ty + 8 * k]);
    }
}

// ---------- router: 32 tokens/block, LDS-aggregated atomics; also emits xb + slot map ----------
__global__ __launch_bounds__(256) void router_kernel(const float* __restrict__ x,
                                                     const float* __restrict__ gw,
                                                     const float* __restrict__ bias,
                                                     int* __restrict__ cnt,     // padded: cnt[e*32]
                                                     int* __restrict__ tok,
                                                     int* __restrict__ slotp,
                                                     float* __restrict__ pg,
                                                     ushort* __restrict__ xb) {
    __shared__ int le[64];
    __shared__ float lg[64];
    __shared__ int lpos[64];
    __shared__ int lcnt[8];
    __shared__ int gbase[8];
    int tid = threadIdx.x, lane = tid & 63, wave = tid >> 6;
    if (tid < 8) lcnt[tid] = 0;
    __syncthreads();
    int t0 = blockIdx.x * 32 + wave * 8;
    for (int it = 0; it < 8; ++it) {
        int t = t0 + it;
        const float4* xr = (const float4*)(x + (size_t)t * Dd);
        float4 xa = xr[lane * 2], xc = xr[lane * 2 + 1];
        ushort4 o1, o2;
        o1.x = f2bf(xa.x); o1.y = f2bf(xa.y); o1.z = f2bf(xa.z); o1.w = f2bf(xa.w);
        o2.x = f2bf(xc.x); o2.y = f2bf(xc.y); o2.z = f2bf(xc.z); o2.w = f2bf(xc.w);
        *(ushort4*)(xb + (size_t)t * Dd + lane * 8) = o1;
        *(ushort4*)(xb + (size_t)t * Dd + lane * 8 + 4) = o2;
        float sc[8];
#pragma unroll
        for (int e = 0; e < 8; ++e) {
            const float4* gr = (const float4*)(gw + (size_t)e * Dd);
            float4 ga = gr[lane * 2], gc = gr[lane * 2 + 1];
            float s = xa.x * ga.x + xa.y * ga.y + xa.z * ga.z + xa.w * ga.w
                    + xc.x * gc.x + xc.y * gc.y + xc.z * gc.z + xc.w * gc.w;
#pragma unroll
            for (int o = 32; o > 0; o >>= 1) s += __shfl_xor(s, o);
            sc[e] = s;
        }
        if (lane == 0) {
            float b0 = -1e30f; int i0 = 0;
#pragma unroll
            for (int e = 0; e < 8; ++e) { float bv = sc[e] + bias[e]; if (bv > b0) { b0 = bv; i0 = e; } }
            float b1v = -1e30f; int i1 = (i0 == 0) ? 1 : 0;
#pragma unroll
            for (int e = 0; e < 8; ++e) if (e != i0) { float bv = sc[e] + bias[e]; if (bv > b1v) { b1v = bv; i1 = e; } }
            float v0 = -1e30f; int k0i = 0;
#pragma unroll
            for (int e = 0; e < 8; ++e) if (sc[e] > v0) { v0 = sc[e]; k0i = e; }
            float v1 = -1e30f;
#pragma unroll
            for (int e = 0; e < 8; ++e) if (e != k0i && sc[e] > v1) v1 = sc[e];
            float p0 = 1.f / (1.f + __expf(-v0));
            float p1 = 1.f / (1.f + __expf(-v1));
            float inv = 1.f / (p0 + p1);
            int ai = (wave * 8 + it) * 2;
            le[ai] = i0;     lg[ai] = p0 * inv;
            le[ai + 1] = i1; lg[ai + 1] = p1 * inv;
        }
    }
    __syncthreads();
    if (tid < 64) lpos[tid] = atomicAdd(&lcnt[le[tid]], 1);
    __syncthreads();
    if (tid < 8) gbase[tid] = atomicAdd(&cnt[tid * 32], lcnt[tid]);
    __syncthreads();
    if (tid < 64) {
        int e = le[tid];
        int dst = gbase[e] + lpos[tid];
        int t = blockIdx.x * 32 + (tid >> 1);
        tok[(size_t)e * Tn + dst] = t;
        slotp[t * 2 + (tid & 1)] = (e << 16) | dst;
        pg[t * 2 + (tid & 1)] = lg[tid];
    }
}

// ---------- scan ----------
__global__ void scan_kernel(const int* cnt, int* off, int* cntc) {
    if (threadIdx.x == 0 && blockIdx.x == 0) {
        int s = 0;
        for (int e = 0; e < 8; ++e) { int c = cnt[e * 32]; cntc[e] = c; off[e] = s; s += c; }
        off[8] = s;
        cntc[8] = Tn;
    }
}

// ---------- 256x256 8-phase GEMM core (bf16, BK=64, 8 waves) ----------
// LDS ring (ushort idx): A[s][h] @ (s*2+h)*8192 ; B[s][h] @ 32768+(s*2+h)*8192.
// Phase schedule per iteration i (K-tiles kt0=2i slot0, kt1=2i+1 slot1):
//   ph1: rdA(s0,m0)+rdB(s0,n0) | st s1.A1 @k0+64  | mm(0,0)
//   ph2: rdB(s0,n1)            | st s1.B1 @k0+64  | mm(0,1)
//   ph3: rdA(s0,m1)            | st s0.A0 @k0+128 | mm(1,0)
//   ph4:                       | st s0.B0 @k0+128 | mm(1,1) vmcnt(4)
//   ph5: rdA(s1,m0)+rdB(s1,n0) | st s0.B1 @k0+128 | mm(0,0)
//   ph6: rdB(s1,n1)            | st s0.A1 @k0+128 | mm(0,1)
//   ph7: rdA(s1,m1)            | st s1.A0 @k0+192 | mm(1,0)
//   ph8:                       | st s1.B0 @k0+192 | mm(1,1) vmcnt(4)
// Every stage targets a half-tile whose last reader finished >=1 closing barrier
// earlier; every read is covered by a vmcnt checkpoint in a strictly earlier
// phase. Tail iteration uses vmcnt(0) (its skipped stages would shift counts).
__device__ __forceinline__ void mm256_core(
        const ushort* (&aSrc)[2][2], const ushort* (&bSrc)[2][2],
        ushort* smem, int KK, f32x4 (&acc)[8][4]) {
    const int tid = threadIdx.x;
    const int lane = tid & 63, wid = tid >> 6;
    const int wm = wid >> 2, wn = wid & 3, hb = wn >> 1, wn1 = wn & 1;
    const int col15 = lane & 15, quad = lane >> 4, sw7 = col15 & 7;

    ushort* Ard = smem + wm * 8192;           // + s*16384
    ushort* Brd = smem + 32768 + hb * 8192;   // + s*16384
    ushort* Adst = smem + wid * 1024;         // + (s*2+h)*8192 + r*512
    ushort* Bdst = smem + 32768 + wid * 1024;

    auto rdA = [&](int s, int mi, int ks) -> short8 {
        return *(const short8*)&Ard[s * 16384 + mi * 1024 + col15 * 64 + (((ks * 4 + quad) ^ sw7) << 3)];
    };
    auto rdB = [&](int s, int ni, int ks) -> short8 {
        return *(const short8*)&Brd[s * 16384 + (wn1 * 64 + ni * 16 + col15) * 64 + (((ks * 4 + quad) ^ sw7) << 3)];
    };
    auto stA = [&](int s, int h, int kb) {
        if (kb < KK) {
            __builtin_amdgcn_global_load_lds((const AS1 void*)(aSrc[h][0] + kb), (AS3 void*)(Adst + (s * 2 + h) * 8192), 16, 0, 0);
            __builtin_amdgcn_global_load_lds((const AS1 void*)(aSrc[h][1] + kb), (AS3 void*)(Adst + (s * 2 + h) * 8192 + 512), 16, 0, 0);
        }
    };
    auto stB = [&](int s, int h, int kb) {
        if (kb < KK) {
            __builtin_amdgcn_global_load_lds((const AS1 void*)(bSrc[h][0] + kb), (AS3 void*)(Bdst + (s * 2 + h) * 8192), 16, 0, 0);
            __builtin_amdgcn_global_load_lds((const AS1 void*)(bSrc[h][1] + kb), (AS3 void*)(Bdst + (s * 2 + h) * 8192 + 512), 16, 0, 0);
        }
    };

    short8 aF[4][2], bF0[2][2], bF1[2][2];
    auto ldA = [&](int s, int mh) {
#pragma unroll
        for (int j = 0; j < 4; ++j) { aF[j][0] = rdA(s, mh * 4 + j, 0); aF[j][1] = rdA(s, mh * 4 + j, 1); }
    };
    auto ldB = [&](int s, int nh, short8 (&bF)[2][2]) {
#pragma unroll
        for (int t = 0; t < 2; ++t) { bF[t][0] = rdB(s, nh * 2 + t, 0); bF[t][1] = rdB(s, nh * 2 + t, 1); }
    };
    auto mmq = [&](int mh, int nh, short8 (&bF)[2][2]) {
        __builtin_amdgcn_s_setprio(1);
#pragma unroll
        for (int j = 0; j < 4; ++j)
#pragma unroll
            for (int t = 0; t < 2; ++t) {
                acc[mh * 4 + j][nh * 2 + t] = __builtin_amdgcn_mfma_f32_16x16x32_bf16(aF[j][0], bF[t][0], acc[mh * 4 + j][nh * 2 + t], 0, 0, 0);
                acc[mh * 4 + j][nh * 2 + t] = __builtin_amdgcn_mfma_f32_16x16x32_bf16(aF[j][1], bF[t][1], acc[mh * 4 + j][nh * 2 + t], 0, 0, 0);
            }
        __builtin_amdgcn_s_setprio(0);
    };

#define BAR()  __builtin_amdgcn_s_barrier()
#define LGK0() do { asm volatile("s_waitcnt lgkmcnt(0)" ::: "memory"); __builtin_amdgcn_sched_barrier(0); } while (0)

    // prologue: full slot0 tile @k=0 + slot1 A0/B0 @k=64 (A0,B0 of s1 stay in flight)
    stA(0, 0, 0); stB(0, 0, 0); stB(0, 1, 0); stA(0, 1, 0);
    stA(1, 0, 64); stB(1, 0, 64);
    asm volatile("s_waitcnt vmcnt(4)" ::: "memory");
    BAR();

    const int NIT = KK >> 7;
    for (int i = 0; i < NIT; ++i) {
        const int k0 = i << 7;
        const bool tail = (i == NIT - 1);
        // ph1
        ldA(0, 0); ldB(0, 0, bF0);
        stA(1, 1, k0 + 64);
        BAR(); LGK0(); mmq(0, 0, bF0); BAR();
        // ph2
        ldB(0, 1, bF1);
        stB(1, 1, k0 + 64);
        BAR(); LGK0(); mmq(0, 1, bF1); BAR();
        // ph3
        ldA(0, 1);
        stA(0, 0, k0 + 128);
        BAR(); LGK0(); mmq(1, 0, bF0); BAR();
        // ph4 (checkpoint)
        stB(0, 0, k0 + 128);
        BAR(); mmq(1, 1, bF1);
        if (tail) asm volatile("s_waitcnt vmcnt(0)" ::: "memory");
        else      asm volatile("s_waitcnt vmcnt(4)" ::: "memory");
        BAR();
        // ph5
        ldA(1, 0); ldB(1, 0, bF0);
        stB(0, 1, k0 + 128);
        BAR(); LGK0(); mmq(0, 0, bF0); BAR();
        // ph6
        ldB(1, 1, bF1);
        stA(0, 1, k0 + 128);
        BAR(); LGK0(); mmq(0, 1, bF1); BAR();
        // ph7
        ldA(1, 1);
        stA(1, 0, k0 + 192);
        BAR(); LGK0(); mmq(1, 0, bF0); BAR();
        // ph8 (checkpoint)
        stB(1, 0, k0 + 192);
        BAR(); mmq(1, 1, bF1);
        if (tail) asm volatile("s_waitcnt vmcnt(0)" ::: "memory");
        else      asm volatile("s_waitcnt vmcnt(4)" ::: "memory");
        BAR();
    }
#undef BAR
#undef LGK0
}

// ---------- stage1: plain GEMM vs interleaved w13 (N=2048), in-lane silu pairing ----------
// grid (32, 8, 9): 256x256 tiles, 512 threads.
__global__ __launch_bounds__(512, 2) void stage1_kernel(
        const ushort* __restrict__ xb, const ushort* __restrict__ w13t,
        const int* __restrict__ tok, const int* __restrict__ cntc,
        const int* __restrict__ off, ushort* __restrict__ Hbuf) {
    __shared__ __align__(16) ushort smem[65536];
    __shared__ int toks[256];
    int e = blockIdx.z;
    int cn = cntc[e];
    int m0 = blockIdx.x * 256;
    if (m0 >= cn) return;
    int n0 = blockIdx.y * 256;
    const ushort* we = w13t + (size_t)e * 2 * Hh * Dd;

    int tid = threadIdx.x;
    if (tid < 256) {
        int slot = m0 + tid;
        int sl = slot < cn ? slot : cn - 1;
        toks[tid] = (e == 8) ? sl : tok[(size_t)e * Tn + sl];
    }
    __syncthreads();

    int lane = tid & 63, wid = tid >> 6;
    int lr = lane >> 3, l7 = lane & 7;
    int lcx = (l7 ^ lr) << 3;

    const ushort* aSrc[2][2];
    const ushort* bSrc[2][2];
#pragma unroll
    for (int h = 0; h < 2; ++h)
#pragma unroll
        for (int r = 0; r < 2; ++r) {
            int row = h * 128 + wid * 16 + r * 8 + lr;
            aSrc[h][r] = xb + (size_t)toks[row] * Dd + lcx;
            bSrc[h][r] = we + (size_t)(n0 + row) * Dd + lcx;
        }

    f32x4 acc[8][4];
#pragma unroll
    for (int a = 0; a < 8; ++a)
#pragma unroll
        for (int b = 0; b < 4; ++b) acc[a][b] = (f32x4){0.f, 0.f, 0.f, 0.f};

    mm256_core(aSrc, bSrc, smem, Dd, acc);

    int wm = wid >> 2, wn = wid & 3;
    int col15 = lane & 15, quad = lane >> 4;
    int oe = off[e];
    int hbase = (n0 >> 1) + wn * 32;
#pragma unroll
    for (int mi = 0; mi < 8; ++mi)
#pragma unroll
        for (int r = 0; r < 4; ++r) {
            int slot = m0 + wm * 128 + mi * 16 + quad * 4 + r;
            if (slot < cn) {
                size_t rowb = (size_t)(oe + slot) * Hh;
#pragma unroll
                for (int np = 0; np < 2; ++np) {
                    float h1 = acc[mi][np * 2][r], h3 = acc[mi][np * 2 + 1][r];
                    float s = h1 / (1.f + __expf(-h1));
                    Hbuf[rowb + hbase + np * 16 + col15] = f2bf(s * h3);
                }
            }
        }
}

// ---------- stage2: Yc[slot] = Hrow @ W2, 256x256 tiles, 8-phase ----------
// grid (32, 2, 9): 512 threads.
__global__ __launch_bounds__(512, 2) void stage2_kernel(
        const ushort* __restrict__ Hbuf, const ushort* __restrict__ w2t,
        const int* __restrict__ cntc, const int* __restrict__ off,
        ushort* __restrict__ Yc) {
    __shared__ __align__(16) ushort smem[65536];
    int e = blockIdx.z;
    int cn = cntc[e];
    int m0 = blockIdx.x * 256;
    if (m0 >= cn) return;
    int n0 = blockIdx.y * 256;
    int oe = off[e];
    const ushort* w2e = w2t + (size_t)e * Dd * Hh;

    int tid = threadIdx.x;
    int lane = tid & 63, wid = tid >> 6;
    int lr = lane >> 3, l7 = lane & 7;
    int lcx = (l7 ^ lr) << 3;

    const ushort* aSrc[2][2];
    const ushort* bSrc[2][2];
#pragma unroll
    for (int h = 0; h < 2; ++h)
#pragma unroll
        for (int r = 0; r < 2; ++r) {
            int row = h * 128 + wid * 16 + r * 8 + lr;
            aSrc[h][r] = Hbuf + (size_t)(oe + m0 + row) * Hh + lcx;  // pad rows read next expert's rows (in-bounds, discarded)
            bSrc[h][r] = w2e + (size_t)(n0 + row) * Hh + lcx;
        }

    f32x4 acc[8][4];
#pragma unroll
    for (int a = 0; a < 8; ++a)
#pragma unroll
        for (int b = 0; b < 4; ++b) acc[a][b] = (f32x4){0.f, 0.f, 0.f, 0.f};

    mm256_core(aSrc, bSrc, smem, Hh, acc);

    int wm = wid >> 2, wn = wid & 3;
    int col15 = lane & 15, quad = lane >> 4;
#pragma unroll
    for (int mi = 0; mi < 8; ++mi)
#pragma unroll
        for (int r = 0; r < 4; ++r) {
            int slot = m0 + wm * 128 + mi * 16 + quad * 4 + r;
            if (slot < cn) {
                size_t rowb = (size_t)(oe + slot) * Dd;
#pragma unroll
                for (int ni = 0; ni < 4; ++ni)
                    Yc[rowb + n0 + wn * 64 + ni * 16 + col15] = f2bf(acc[mi][ni][r]);
            }
        }
}

// ---------- combine: out[t] = g0*Yc[s0] + g1*Yc[s1] + Yc[shared+t] ----------
__global__ __launch_bounds__(256) void combine_kernel(const ushort* __restrict__ Yc,
        const int* __restrict__ slotp, const float* __restrict__ pg,
        const int* __restrict__ off, float* __restrict__ out) {
    int g = blockIdx.x * 256 + threadIdx.x;
    int t = g >> 6;
    int c = (g & 63) * 8;
    int p0 = slotp[t * 2], p1 = slotp[t * 2 + 1];
    float g0 = pg[t * 2], g1 = pg[t * 2 + 1];
    int s0 = off[p0 >> 16] + (p0 & 0xffff);
    int s1 = off[p1 >> 16] + (p1 & 0xffff);
    int s2 = off[8] + t;
    short8 a = *(const short8*)(Yc + (size_t)s0 * Dd + c);
    short8 b = *(const short8*)(Yc + (size_t)s1 * Dd + c);
    short8 d = *(const short8*)(Yc + (size_t)s2 * Dd + c);
    float o[8];
#pragma unroll
    for (int i = 0; i < 8; ++i)
        o[i] = g0 * bf2f(a[i]) + g1 * bf2f(b[i]) + bf2f(d[i]);
    float* dst = out + (size_t)t * Dd + c;
    *(float4*)dst = (float4){o[0], o[1], o[2], o[3]};
    *(float4*)(dst + 4) = (float4){o[4], o[5], o[6], o[7]};
}

extern "C" void kernel_launch(void* const* d_in, const int* in_sizes, int n_in,
                              void* d_out, int out_size, void* d_ws, size_t ws_size,
                              hipStream_t stream) {
    (void)in_sizes; (void)n_in; (void)out_size; (void)ws_size;
    const float* x    = (const float*)d_in[0];
    const float* gw   = (const float*)d_in[1];
    const float* bias = (const float*)d_in[2];
    const float* w1   = (const float*)d_in[3];
    const float* w3   = (const float*)d_in[4];
    const float* w2   = (const float*)d_in[5];
    const float* sw1  = (const float*)d_in[6];
    const float* sw3  = (const float*)d_in[7];
    const float* sw2  = (const float*)d_in[8];
    float* out = (float*)d_out;

    char* ws = (char*)d_ws;
    ushort* xb    = (ushort*)(ws + OFF_XB);
    ushort* w13t  = (ushort*)(ws + OFF_W13T);
    ushort* w2t   = (ushort*)(ws + OFF_W2T);
    ushort* Hbuf  = (ushort*)(ws + OFF_HBUF);
    ushort* Yc    = (ushort*)(ws + OFF_YC);
    int*    tok   = (int*)(ws + OFF_TOK);
    int*    slotp = (int*)(ws + OFF_SLOTP);
    float*  pg    = (float*)(ws + OFF_PG);
    int*    cnt   = (int*)(ws + OFF_CNT);
    int*    off   = (int*)(ws + OFF_OFFS);
    int*    cntc  = off + 16;

    hipMemsetAsync(cnt, 0, 1024, stream);

    trans_kernel<<<dim3(32, 16, 27), 256, 0, stream>>>(w1, sw1, w3, sw3, w2, sw2, w13t, w2t);
    router_kernel<<<256, 256, 0, stream>>>(x, gw, bias, cnt, tok, slotp, pg, xb);
    scan_kernel<<<1, 64, 0, stream>>>(cnt, off, cntc);

    stage1_kernel<<<dim3(32, 8, NEx), 512, 0, stream>>>(xb, w13t, tok, cntc, off, Hbuf);
    stage2_kernel<<<dim3(32, Dd / 256, NEx), 512, 0, stream>>>(Hbuf, w2t, cntc, off, Yc);
    combine_kernel<<<2048, 256, 0, stream>>>(Yc, slotp, pg, off, out);
}

// Round 2
// 332.353 us; speedup vs baseline: 1.1747x; 1.1747x over previous
//
#include <hip/hip_runtime.h>
#include <hip/hip_bf16.h>

// DSMoE: B=4,S=2048 -> T=8192 tokens, D=512, H=1024, E=8 routed (top-2) + shared.
// bf16 MFMA token-gather MoE; shared expert folded in as expert 8.
// R8: R6 base (128x128 tiles) + minimal 2-phase pipeline in stage1/stage2:
//     explicit LDS double-buffer, prefetch next K-tile BEFORE computing current,
//     ONE __syncthreads per K-step (its vmcnt(0) drain covers the prefetch).

#define Tn 8192
#define Dd 512
#define Hh 1024
#define NEx 9

typedef __attribute__((ext_vector_type(8))) short short8;
typedef __attribute__((ext_vector_type(4))) float f32x4;

#define AS1 __attribute__((address_space(1)))
#define AS3 __attribute__((address_space(3)))

#define OFF_XB    ((size_t)0)
#define OFF_W13T  (OFF_XB + (size_t)Tn * Dd * 2)
#define OFF_W2T   (OFF_W13T + (size_t)NEx * 2 * Hh * Dd * 2)
#define OFF_HBUF  (OFF_W2T + (size_t)NEx * Dd * Hh * 2)
#define OFF_TOK   (OFF_HBUF + (size_t)(3 * Tn) * Hh * 2)
#define OFF_SLOTP (OFF_TOK + (size_t)8 * Tn * 4)
#define OFF_PG    (OFF_SLOTP + (size_t)Tn * 2 * 4)
#define OFF_CNT   (OFF_PG + (size_t)Tn * 2 * 4)       // 8 counters, 128B apart
#define OFF_OFFS  (OFF_CNT + 1024)                    // off[9] then cntc[9]
#define OFF_YC    OFF_XB   // alias: Yc (25.2MB) over xb+w13t (26.9MB), dead by stage2

__device__ __forceinline__ ushort f2bf(float f) {
    unsigned int u = __float_as_uint(f);
    return (ushort)((u + 0x7fffu + ((u >> 16) & 1u)) >> 16);
}
__device__ __forceinline__ float bf2f(short s) {
    return __uint_as_float(((unsigned int)(unsigned short)s) << 16);
}

// ---------- fused transpose: 27 slices; fam 0/1 interleave into w13t ----------
// fam 0: w1, fam 1: w3 -> w13t rows n = ((h>>4)*2+fam)*16 + (h&15); fam 2: w2 plain.
__global__ __launch_bounds__(256) void trans_kernel(
        const float* __restrict__ w1, const float* __restrict__ sw1,
        const float* __restrict__ w3, const float* __restrict__ sw3,
        const float* __restrict__ w2, const float* __restrict__ sw2,
        ushort* __restrict__ w13t, ushort* __restrict__ w2t) {
    __shared__ float tile[32][33];
    int z = blockIdx.z;
    int fam = z / 9, sl = z - fam * 9;
    int tx = threadIdx.x & 31, ty = threadIdx.x >> 5;
    if (fam < 2) {
        const float* base = (fam == 0) ? ((sl < 8) ? w1 + (size_t)sl * Dd * Hh : sw1)
                                       : ((sl < 8) ? w3 + (size_t)sl * Dd * Hh : sw3);
        ushort* dst = w13t + (size_t)sl * 2 * Hh * Dd;
        int c0 = blockIdx.x * 32, r0 = blockIdx.y * 32;   // c: hidden, r: dim
#pragma unroll
        for (int k = 0; k < 4; ++k)
            tile[ty + 8 * k][tx] = base[(size_t)(r0 + ty + 8 * k) * Hh + c0 + tx];
        __syncthreads();
#pragma unroll
        for (int k = 0; k < 4; ++k) {
            int h = c0 + ty + 8 * k;
            int n = (((h >> 4) * 2 + fam) << 4) + (h & 15);
            dst[(size_t)n * Dd + r0 + tx] = f2bf(tile[tx][ty + 8 * k]);
        }
    } else {
        const float* base = (sl < 8) ? w2 + (size_t)sl * Dd * Hh : sw2;
        ushort* dst = w2t + (size_t)sl * Dd * Hh;
        int r0 = blockIdx.x * 32, c0 = blockIdx.y * 32;   // r: hidden, c: dim
#pragma unroll
        for (int k = 0; k < 4; ++k)
            tile[ty + 8 * k][tx] = base[(size_t)(r0 + ty + 8 * k) * Dd + c0 + tx];
        __syncthreads();
#pragma unroll
        for (int k = 0; k < 4; ++k)
            dst[(size_t)(c0 + ty + 8 * k) * Hh + r0 + tx] = f2bf(tile[tx][ty + 8 * k]);
    }
}

// ---------- router: 32 tokens/block, LDS-aggregated atomics; also emits xb + slot map ----------
__global__ __launch_bounds__(256) void router_kernel(const float* __restrict__ x,
                                                     const float* __restrict__ gw,
                                                     const float* __restrict__ bias,
                                                     int* __restrict__ cnt,     // padded: cnt[e*32]
                                                     int* __restrict__ tok,
                                                     int* __restrict__ slotp,
                                                     float* __restrict__ pg,
                                                     ushort* __restrict__ xb) {
    __shared__ int le[64];
    __shared__ float lg[64];
    __shared__ int lpos[64];
    __shared__ int lcnt[8];
    __shared__ int gbase[8];
    int tid = threadIdx.x, lane = tid & 63, wave = tid >> 6;
    if (tid < 8) lcnt[tid] = 0;
    __syncthreads();
    int t0 = blockIdx.x * 32 + wave * 8;
    for (int it = 0; it < 8; ++it) {
        int t = t0 + it;
        const float4* xr = (const float4*)(x + (size_t)t * Dd);
        float4 xa = xr[lane * 2], xc = xr[lane * 2 + 1];
        ushort4 o1, o2;
        o1.x = f2bf(xa.x); o1.y = f2bf(xa.y); o1.z = f2bf(xa.z); o1.w = f2bf(xa.w);
        o2.x = f2bf(xc.x); o2.y = f2bf(xc.y); o2.z = f2bf(xc.z); o2.w = f2bf(xc.w);
        *(ushort4*)(xb + (size_t)t * Dd + lane * 8) = o1;
        *(ushort4*)(xb + (size_t)t * Dd + lane * 8 + 4) = o2;
        float sc[8];
#pragma unroll
        for (int e = 0; e < 8; ++e) {
            const float4* gr = (const float4*)(gw + (size_t)e * Dd);
            float4 ga = gr[lane * 2], gc = gr[lane * 2 + 1];
            float s = xa.x * ga.x + xa.y * ga.y + xa.z * ga.z + xa.w * ga.w
                    + xc.x * gc.x + xc.y * gc.y + xc.z * gc.z + xc.w * gc.w;
#pragma unroll
            for (int o = 32; o > 0; o >>= 1) s += __shfl_xor(s, o);
            sc[e] = s;
        }
        if (lane == 0) {
            float b0 = -1e30f; int i0 = 0;
#pragma unroll
            for (int e = 0; e < 8; ++e) { float bv = sc[e] + bias[e]; if (bv > b0) { b0 = bv; i0 = e; } }
            float b1v = -1e30f; int i1 = (i0 == 0) ? 1 : 0;
#pragma unroll
            for (int e = 0; e < 8; ++e) if (e != i0) { float bv = sc[e] + bias[e]; if (bv > b1v) { b1v = bv; i1 = e; } }
            float v0 = -1e30f; int k0i = 0;
#pragma unroll
            for (int e = 0; e < 8; ++e) if (sc[e] > v0) { v0 = sc[e]; k0i = e; }
            float v1 = -1e30f;
#pragma unroll
            for (int e = 0; e < 8; ++e) if (e != k0i && sc[e] > v1) v1 = sc[e];
            float p0 = 1.f / (1.f + __expf(-v0));
            float p1 = 1.f / (1.f + __expf(-v1));
            float inv = 1.f / (p0 + p1);
            int ai = (wave * 8 + it) * 2;
            le[ai] = i0;     lg[ai] = p0 * inv;
            le[ai + 1] = i1; lg[ai + 1] = p1 * inv;
        }
    }
    __syncthreads();
    if (tid < 64) lpos[tid] = atomicAdd(&lcnt[le[tid]], 1);
    __syncthreads();
    if (tid < 8) gbase[tid] = atomicAdd(&cnt[tid * 32], lcnt[tid]);
    __syncthreads();
    if (tid < 64) {
        int e = le[tid];
        int dst = gbase[e] + lpos[tid];
        int t = blockIdx.x * 32 + (tid >> 1);
        tok[(size_t)e * Tn + dst] = t;
        slotp[t * 2 + (tid & 1)] = (e << 16) | dst;
        pg[t * 2 + (tid & 1)] = lg[tid];
    }
}

// ---------- scan ----------
__global__ void scan_kernel(const int* cnt, int* off, int* cntc) {
    if (threadIdx.x == 0 && blockIdx.x == 0) {
        int s = 0;
        for (int e = 0; e < 8; ++e) { int c = cnt[e * 32]; cntc[e] = c; off[e] = s; s += c; }
        off[8] = s;
        cntc[8] = Tn;
    }
}

// ---------- stage1: plain GEMM vs interleaved w13 (N=2048), in-lane silu pairing ----------
// grid (64, 16, 9): x=row-block (pins XCD), y=n-block(128 interleaved cols = 64 hidden).
// 2-phase dbuf: prefetch K-tile k+1 while MFMA on k; ONE barrier per K-step.
__global__ __launch_bounds__(256, 2) void stage1_kernel(
        const ushort* __restrict__ xb, const ushort* __restrict__ w13t,
        const int* __restrict__ tok, const int* __restrict__ cntc,
        const int* __restrict__ off, ushort* __restrict__ Hbuf) {
    int e = blockIdx.z;
    int cn = cntc[e];
    int m0 = blockIdx.x * 128;
    if (m0 >= cn) return;
    int n0 = blockIdx.y * 128;
    const ushort* we = w13t + (size_t)e * 2 * Hh * Dd;

    __shared__ ushort As[2][128 * 64];
    __shared__ ushort Bs[2][128 * 64];
    __shared__ int toks[128];

    int tid = threadIdx.x;
    if (tid < 128) {
        int slot = m0 + tid;
        int sl = slot < cn ? slot : cn - 1;
        toks[tid] = (e == 8) ? sl : tok[(size_t)e * Tn + sl];
    }
    __syncthreads();

    int lane = tid & 63, wave = tid >> 6;
    int wm = (wave & 1) * 64, wn = (wave >> 1) * 64;
    int col15 = lane & 15, quad = lane >> 4;
    int lr = lane >> 3;                 // row within 8-row chunk (staging)
    int lcx = ((lane & 7) ^ lr) * 8;    // swizzled logical k-offset (shorts)

    f32x4 acc[4][4];
#pragma unroll
    for (int a = 0; a < 4; ++a)
#pragma unroll
        for (int b = 0; b < 4; ++b) acc[a][b] = (f32x4){0.f, 0.f, 0.f, 0.f};

    auto stage = [&](int buf, int kb) {
#pragma unroll
        for (int i = 0; i < 4; ++i) {
            int cid = wave * 4 + i;
            const ushort* g = xb + (size_t)toks[cid * 8 + lr] * Dd + kb + lcx;
            __builtin_amdgcn_global_load_lds((const AS1 void*)g, (AS3 void*)(&As[buf][cid * 512]), 16, 0, 0);
        }
#pragma unroll
        for (int i = 0; i < 4; ++i) {
            int cid = wave * 4 + i;
            const ushort* g = we + (size_t)(n0 + cid * 8 + lr) * Dd + kb + lcx;
            __builtin_amdgcn_global_load_lds((const AS1 void*)g, (AS3 void*)(&Bs[buf][cid * 512]), 16, 0, 0);
        }
    };

    stage(0, 0);
    __syncthreads();
    int cur = 0;
    for (int kb = 0; kb < Dd; kb += 64) {
        if (kb + 64 < Dd) stage(cur ^ 1, kb + 64);
#pragma unroll
        for (int ks = 0; ks < 2; ++ks) {
            int px = ((ks * 4 + quad) ^ (col15 & 7)) * 8;   // swizzled k-offset (shorts)
            short8 a[4], b[4];
#pragma unroll
            for (int mi = 0; mi < 4; ++mi)
                a[mi] = *(const short8*)&As[cur][(wm + mi * 16 + col15) * 64 + px];
#pragma unroll
            for (int ni = 0; ni < 4; ++ni)
                b[ni] = *(const short8*)&Bs[cur][(wn + ni * 16 + col15) * 64 + px];
#pragma unroll
            for (int mi = 0; mi < 4; ++mi)
#pragma unroll
                for (int ni = 0; ni < 4; ++ni)
                    acc[mi][ni] = __builtin_amdgcn_mfma_f32_16x16x32_bf16(a[mi], b[ni], acc[mi][ni], 0, 0, 0);
        }
        __syncthreads();   // drains prefetch vmcnt + protects buffer reuse
        cur ^= 1;
    }

    int oe = off[e];
    int hbase = (n0 + wn) >> 1;         // cols ni={0,1} -> h block 0, ni={2,3} -> h block 1
#pragma unroll
    for (int mi = 0; mi < 4; ++mi)
#pragma unroll
        for (int r = 0; r < 4; ++r) {
            int slot = m0 + wm + mi * 16 + quad * 4 + r;   // C layout: row = quad*4+reg
            if (slot < cn) {
                size_t rowb = (size_t)(oe + slot) * Hh;
#pragma unroll
                for (int np = 0; np < 2; ++np) {
                    float h1 = acc[mi][np * 2][r], h3 = acc[mi][np * 2 + 1][r];
                    float s = h1 / (1.f + __expf(-h1));
                    Hbuf[rowb + hbase + np * 16 + col15] = f2bf(s * h3);
                }
            }
        }
}

// ---------- stage2: Yc[slot] = Hrow @ W2, tile 128x128, BK=64, 2-phase dbuf ----------
// grid (64, 4, 9): x=row-block (pins XCD), y=n-block(128 cols).
__global__ __launch_bounds__(256, 2) void stage2_kernel(
        const ushort* __restrict__ Hbuf, const ushort* __restrict__ w2t,
        const int* __restrict__ cntc, const int* __restrict__ off,
        ushort* __restrict__ Yc) {
    int e = blockIdx.z;
    int cn = cntc[e];
    int m0 = blockIdx.x * 128;
    if (m0 >= cn) return;
    int n0 = blockIdx.y * 128;
    int oe = off[e];
    const ushort* w2e = w2t + (size_t)e * Dd * Hh;

    __shared__ ushort As[2][128 * 64];
    __shared__ ushort Bs[2][128 * 64];

    int tid = threadIdx.x;
    int lane = tid & 63, wave = tid >> 6;
    int wm = (wave & 1) * 64, wn = (wave >> 1) * 64;
    int col15 = lane & 15, quad = lane >> 4;
    int lr = lane >> 3;
    int lcx = ((lane & 7) ^ lr) * 8;

    f32x4 acc[4][4];
#pragma unroll
    for (int a = 0; a < 4; ++a)
#pragma unroll
        for (int b = 0; b < 4; ++b) acc[a][b] = (f32x4){0.f, 0.f, 0.f, 0.f};

    auto stage = [&](int buf, int kb) {
#pragma unroll
        for (int i = 0; i < 4; ++i) {
            int cid = wave * 4 + i;
            const ushort* g = Hbuf + (size_t)(oe + m0 + cid * 8 + lr) * Hh + kb + lcx;
            __builtin_amdgcn_global_load_lds((const AS1 void*)g, (AS3 void*)(&As[buf][cid * 512]), 16, 0, 0);
        }
#pragma unroll
        for (int i = 0; i < 4; ++i) {
            int cid = wave * 4 + i;
            const ushort* g = w2e + (size_t)(n0 + cid * 8 + lr) * Hh + kb + lcx;
            __builtin_amdgcn_global_load_lds((const AS1 void*)g, (AS3 void*)(&Bs[buf][cid * 512]), 16, 0, 0);
        }
    };

    stage(0, 0);
    __syncthreads();
    int cur = 0;
    for (int kb = 0; kb < Hh; kb += 64) {
        if (kb + 64 < Hh) stage(cur ^ 1, kb + 64);
#pragma unroll
        for (int ks = 0; ks < 2; ++ks) {
            int px = ((ks * 4 + quad) ^ (col15 & 7)) * 8;
            short8 a[4], b[4];
#pragma unroll
            for (int mi = 0; mi < 4; ++mi)
                a[mi] = *(const short8*)&As[cur][(wm + mi * 16 + col15) * 64 + px];
#pragma unroll
            for (int ni = 0; ni < 4; ++ni)
                b[ni] = *(const short8*)&Bs[cur][(wn + ni * 16 + col15) * 64 + px];
#pragma unroll
            for (int mi = 0; mi < 4; ++mi)
#pragma unroll
                for (int ni = 0; ni < 4; ++ni)
                    acc[mi][ni] = __builtin_amdgcn_mfma_f32_16x16x32_bf16(a[mi], b[ni], acc[mi][ni], 0, 0, 0);
        }
        __syncthreads();
        cur ^= 1;
    }

#pragma unroll
    for (int mi = 0; mi < 4; ++mi)
#pragma unroll
        for (int r = 0; r < 4; ++r) {
            int slot = m0 + wm + mi * 16 + quad * 4 + r;
            if (slot < cn) {
                size_t rowb = (size_t)(oe + slot) * Dd;
#pragma unroll
                for (int ni = 0; ni < 4; ++ni)
                    Yc[rowb + n0 + wn + ni * 16 + col15] = f2bf(acc[mi][ni][r]);
            }
        }
}

// ---------- combine: out[t] = g0*Yc[s0] + g1*Yc[s1] + Yc[shared+t] ----------
__global__ __launch_bounds__(256) void combine_kernel(const ushort* __restrict__ Yc,
        const int* __restrict__ slotp, const float* __restrict__ pg,
        const int* __restrict__ off, float* __restrict__ out) {
    int g = blockIdx.x * 256 + threadIdx.x;
    int t = g >> 6;
    int c = (g & 63) * 8;
    int p0 = slotp[t * 2], p1 = slotp[t * 2 + 1];
    float g0 = pg[t * 2], g1 = pg[t * 2 + 1];
    int s0 = off[p0 >> 16] + (p0 & 0xffff);
    int s1 = off[p1 >> 16] + (p1 & 0xffff);
    int s2 = off[8] + t;
    short8 a = *(const short8*)(Yc + (size_t)s0 * Dd + c);
    short8 b = *(const short8*)(Yc + (size_t)s1 * Dd + c);
    short8 d = *(const short8*)(Yc + (size_t)s2 * Dd + c);
    float o[8];
#pragma unroll
    for (int i = 0; i < 8; ++i)
        o[i] = g0 * bf2f(a[i]) + g1 * bf2f(b[i]) + bf2f(d[i]);
    float* dst = out + (size_t)t * Dd + c;
    *(float4*)dst = (float4){o[0], o[1], o[2], o[3]};
    *(float4*)(dst + 4) = (float4){o[4], o[5], o[6], o[7]};
}

extern "C" void kernel_launch(void* const* d_in, const int* in_sizes, int n_in,
                              void* d_out, int out_size, void* d_ws, size_t ws_size,
                              hipStream_t stream) {
    (void)in_sizes; (void)n_in; (void)out_size; (void)ws_size;
    const float* x    = (const float*)d_in[0];
    const float* gw   = (const float*)d_in[1];
    const float* bias = (const float*)d_in[2];
    const float* w1   = (const float*)d_in[3];
    const float* w3   = (const float*)d_in[4];
    const float* w2   = (const float*)d_in[5];
    const float* sw1  = (const float*)d_in[6];
    const float* sw3  = (const float*)d_in[7];
    const float* sw2  = (const float*)d_in[8];
    float* out = (float*)d_out;

    char* ws = (char*)d_ws;
    ushort* xb    = (ushort*)(ws + OFF_XB);
    ushort* w13t  = (ushort*)(ws + OFF_W13T);
    ushort* w2t   = (ushort*)(ws + OFF_W2T);
    ushort* Hbuf  = (ushort*)(ws + OFF_HBUF);
    ushort* Yc    = (ushort*)(ws + OFF_YC);
    int*    tok   = (int*)(ws + OFF_TOK);
    int*    slotp = (int*)(ws + OFF_SLOTP);
    float*  pg    = (float*)(ws + OFF_PG);
    int*    cnt   = (int*)(ws + OFF_CNT);
    int*    off   = (int*)(ws + OFF_OFFS);
    int*    cntc  = off + 16;

    hipMemsetAsync(cnt, 0, 1024, stream);

    trans_kernel<<<dim3(32, 16, 27), 256, 0, stream>>>(w1, sw1, w3, sw3, w2, sw2, w13t, w2t);
    router_kernel<<<256, 256, 0, stream>>>(x, gw, bias, cnt, tok, slotp, pg, xb);
    scan_kernel<<<1, 64, 0, stream>>>(cnt, off, cntc);

    stage1_kernel<<<dim3(64, 16, NEx), 256, 0, stream>>>(xb, w13t, tok, cntc, off, Hbuf);
    stage2_kernel<<<dim3(64, Dd / 128, NEx), 256, 0, stream>>>(Hbuf, w2t, cntc, off, Yc);
    combine_kernel<<<2048, 256, 0, stream>>>(Yc, slotp, pg, off, out);
}

// Round 4
// 240.063 us; speedup vs baseline: 1.6264x; 1.3844x over previous
//
#include <hip/hip_runtime.h>
#include <hip/hip_bf16.h>

// DSMoE: B=4,S=2048 -> T=8192 tokens, D=512, H=1024, E=8 routed (top-2) + shared.
// bf16 MFMA token-gather MoE; shared expert folded in as expert 8.
// R9b: resubmit of R9 (container infra failure, no signal). Exact R6 kernel
//     bodies (263us best) + expert->XCD pinned 1-D grid for stage1/stage2:
//     blockIdx%8 == XCD == expert, shared expert row-split 8-way. Per-XCD
//     working set (~4MB) fits L2 -> staging becomes L2-hit instead of thrash.

#define Tn 8192
#define Dd 512
#define Hh 1024
#define NEx 9

typedef __attribute__((ext_vector_type(8))) short short8;
typedef __attribute__((ext_vector_type(4))) float f32x4;

#define AS1 __attribute__((address_space(1)))
#define AS3 __attribute__((address_space(3)))

#define OFF_XB    ((size_t)0)
#define OFF_W13T  (OFF_XB + (size_t)Tn * Dd * 2)
#define OFF_W2T   (OFF_W13T + (size_t)NEx * 2 * Hh * Dd * 2)
#define OFF_HBUF  (OFF_W2T + (size_t)NEx * Dd * Hh * 2)
#define OFF_TOK   (OFF_HBUF + (size_t)(3 * Tn) * Hh * 2)
#define OFF_SLOTP (OFF_TOK + (size_t)8 * Tn * 4)
#define OFF_PG    (OFF_SLOTP + (size_t)Tn * 2 * 4)
#define OFF_CNT   (OFF_PG + (size_t)Tn * 2 * 4)       // 8 counters, 128B apart
#define OFF_OFFS  (OFF_CNT + 1024)                    // off[9] then cntc[9]
#define OFF_YC    OFF_XB   // alias: Yc (25.2MB) over xb+w13t (26.9MB), dead by stage2

__device__ __forceinline__ ushort f2bf(float f) {
    unsigned int u = __float_as_uint(f);
    return (ushort)((u + 0x7fffu + ((u >> 16) & 1u)) >> 16);
}
__device__ __forceinline__ float bf2f(short s) {
    return __uint_as_float(((unsigned int)(unsigned short)s) << 16);
}

// ---------- fused transpose: 27 slices; fam 0/1 interleave into w13t ----------
// fam 0: w1, fam 1: w3 -> w13t rows n = ((h>>4)*2+fam)*16 + (h&15); fam 2: w2 plain.
__global__ __launch_bounds__(256) void trans_kernel(
        const float* __restrict__ w1, const float* __restrict__ sw1,
        const float* __restrict__ w3, const float* __restrict__ sw3,
        const float* __restrict__ w2, const float* __restrict__ sw2,
        ushort* __restrict__ w13t, ushort* __restrict__ w2t) {
    __shared__ float tile[32][33];
    int z = blockIdx.z;
    int fam = z / 9, sl = z - fam * 9;
    int tx = threadIdx.x & 31, ty = threadIdx.x >> 5;
    if (fam < 2) {
        const float* base = (fam == 0) ? ((sl < 8) ? w1 + (size_t)sl * Dd * Hh : sw1)
                                       : ((sl < 8) ? w3 + (size_t)sl * Dd * Hh : sw3);
        ushort* dst = w13t + (size_t)sl * 2 * Hh * Dd;
        int c0 = blockIdx.x * 32, r0 = blockIdx.y * 32;   // c: hidden, r: dim
#pragma unroll
        for (int k = 0; k < 4; ++k)
            tile[ty + 8 * k][tx] = base[(size_t)(r0 + ty + 8 * k) * Hh + c0 + tx];
        __syncthreads();
#pragma unroll
        for (int k = 0; k < 4; ++k) {
            int h = c0 + ty + 8 * k;
            int n = (((h >> 4) * 2 + fam) << 4) + (h & 15);
            dst[(size_t)n * Dd + r0 + tx] = f2bf(tile[tx][ty + 8 * k]);
        }
    } else {
        const float* base = (sl < 8) ? w2 + (size_t)sl * Dd * Hh : sw2;
        ushort* dst = w2t + (size_t)sl * Dd * Hh;
        int r0 = blockIdx.x * 32, c0 = blockIdx.y * 32;   // r: hidden, c: dim
#pragma unroll
        for (int k = 0; k < 4; ++k)
            tile[ty + 8 * k][tx] = base[(size_t)(r0 + ty + 8 * k) * Dd + c0 + tx];
        __syncthreads();
#pragma unroll
        for (int k = 0; k < 4; ++k)
            dst[(size_t)(c0 + ty + 8 * k) * Hh + r0 + tx] = f2bf(tile[tx][ty + 8 * k]);
    }
}

// ---------- router: 32 tokens/block, LDS-aggregated atomics; also emits xb + slot map ----------
__global__ __launch_bounds__(256) void router_kernel(const float* __restrict__ x,
                                                     const float* __restrict__ gw,
                                                     const float* __restrict__ bias,
                                                     int* __restrict__ cnt,     // padded: cnt[e*32]
                                                     int* __restrict__ tok,
                                                     int* __restrict__ slotp,
                                                     float* __restrict__ pg,
                                                     ushort* __restrict__ xb) {
    __shared__ int le[64];
    __shared__ float lg[64];
    __shared__ int lpos[64];
    __shared__ int lcnt[8];
    __shared__ int gbase[8];
    int tid = threadIdx.x, lane = tid & 63, wave = tid >> 6;
    if (tid < 8) lcnt[tid] = 0;
    __syncthreads();
    int t0 = blockIdx.x * 32 + wave * 8;
    for (int it = 0; it < 8; ++it) {
        int t = t0 + it;
        const float4* xr = (const float4*)(x + (size_t)t * Dd);
        float4 xa = xr[lane * 2], xc = xr[lane * 2 + 1];
        ushort4 o1, o2;
        o1.x = f2bf(xa.x); o1.y = f2bf(xa.y); o1.z = f2bf(xa.z); o1.w = f2bf(xa.w);
        o2.x = f2bf(xc.x); o2.y = f2bf(xc.y); o2.z = f2bf(xc.z); o2.w = f2bf(xc.w);
        *(ushort4*)(xb + (size_t)t * Dd + lane * 8) = o1;
        *(ushort4*)(xb + (size_t)t * Dd + lane * 8 + 4) = o2;
        float sc[8];
#pragma unroll
        for (int e = 0; e < 8; ++e) {
            const float4* gr = (const float4*)(gw + (size_t)e * Dd);
            float4 ga = gr[lane * 2], gc = gr[lane * 2 + 1];
            float s = xa.x * ga.x + xa.y * ga.y + xa.z * ga.z + xa.w * ga.w
                    + xc.x * gc.x + xc.y * gc.y + xc.z * gc.z + xc.w * gc.w;
#pragma unroll
            for (int o = 32; o > 0; o >>= 1) s += __shfl_xor(s, o);
            sc[e] = s;
        }
        if (lane == 0) {
            float b0 = -1e30f; int i0 = 0;
#pragma unroll
            for (int e = 0; e < 8; ++e) { float bv = sc[e] + bias[e]; if (bv > b0) { b0 = bv; i0 = e; } }
            float b1v = -1e30f; int i1 = (i0 == 0) ? 1 : 0;
#pragma unroll
            for (int e = 0; e < 8; ++e) if (e != i0) { float bv = sc[e] + bias[e]; if (bv > b1v) { b1v = bv; i1 = e; } }
            float v0 = -1e30f; int k0i = 0;
#pragma unroll
            for (int e = 0; e < 8; ++e) if (sc[e] > v0) { v0 = sc[e]; k0i = e; }
            float v1 = -1e30f;
#pragma unroll
            for (int e = 0; e < 8; ++e) if (e != k0i && sc[e] > v1) v1 = sc[e];
            float p0 = 1.f / (1.f + __expf(-v0));
            float p1 = 1.f / (1.f + __expf(-v1));
            float inv = 1.f / (p0 + p1);
            int ai = (wave * 8 + it) * 2;
            le[ai] = i0;     lg[ai] = p0 * inv;
            le[ai + 1] = i1; lg[ai + 1] = p1 * inv;
        }
    }
    __syncthreads();
    if (tid < 64) lpos[tid] = atomicAdd(&lcnt[le[tid]], 1);
    __syncthreads();
    if (tid < 8) gbase[tid] = atomicAdd(&cnt[tid * 32], lcnt[tid]);
    __syncthreads();
    if (tid < 64) {
        int e = le[tid];
        int dst = gbase[e] + lpos[tid];
        int t = blockIdx.x * 32 + (tid >> 1);
        tok[(size_t)e * Tn + dst] = t;
        slotp[t * 2 + (tid & 1)] = (e << 16) | dst;
        pg[t * 2 + (tid & 1)] = lg[tid];
    }
}

// ---------- scan ----------
__global__ void scan_kernel(const int* cnt, int* off, int* cntc) {
    if (threadIdx.x == 0 && blockIdx.x == 0) {
        int s = 0;
        for (int e = 0; e < 8; ++e) { int c = cnt[e * 32]; cntc[e] = c; off[e] = s; s += c; }
        off[8] = s;
        cntc[8] = Tn;
    }
}

// ---------- stage1: plain GEMM vs interleaved w13 (N=2048), in-lane silu pairing ----------
// 1-D grid, 9216 blocks. XCD-pinned decode: xcd = b&7.
//   slot<1024: routed expert e=xcd, x=slot>>4 (0..63), y=slot&15.
//   else: shared e=8, s=slot-1024 (0..127), x=xcd*8+(s>>4), y=s&15.
__global__ __launch_bounds__(256, 2) void stage1_kernel(
        const ushort* __restrict__ xb, const ushort* __restrict__ w13t,
        const int* __restrict__ tok, const int* __restrict__ cntc,
        const int* __restrict__ off, ushort* __restrict__ Hbuf) {
    int b = blockIdx.x;
    int xcd = b & 7, slot = b >> 3;
    int e, xblk, yblk;
    if (slot < 1024) { e = xcd; xblk = slot >> 4; yblk = slot & 15; }
    else { int s = slot - 1024; e = 8; xblk = (xcd << 3) + (s >> 4); yblk = s & 15; }
    int cn = cntc[e];
    int m0 = xblk * 128;
    if (m0 >= cn) return;
    int n0 = yblk * 128;
    const ushort* we = w13t + (size_t)e * 2 * Hh * Dd;

    __shared__ ushort As[128 * 64];
    __shared__ ushort Bs[128 * 64];
    __shared__ int toks[128];

    int tid = threadIdx.x;
    if (tid < 128) {
        int sl2 = m0 + tid;
        int sl = sl2 < cn ? sl2 : cn - 1;
        toks[tid] = (e == 8) ? sl : tok[(size_t)e * Tn + sl];
    }
    __syncthreads();

    int lane = tid & 63, wave = tid >> 6;
    int wm = (wave & 1) * 64, wn = (wave >> 1) * 64;
    int col15 = lane & 15, quad = lane >> 4;
    int lr = lane >> 3;                 // row within 8-row chunk (staging)
    int lcx = ((lane & 7) ^ lr) * 8;    // swizzled logical k-offset (shorts)

    f32x4 acc[4][4];
#pragma unroll
    for (int a = 0; a < 4; ++a)
#pragma unroll
        for (int b2 = 0; b2 < 4; ++b2) acc[a][b2] = (f32x4){0.f, 0.f, 0.f, 0.f};

    for (int kb = 0; kb < Dd; kb += 64) {
#pragma unroll
        for (int i = 0; i < 4; ++i) {
            int cid = wave * 4 + i;
            const ushort* g = xb + (size_t)toks[cid * 8 + lr] * Dd + kb + lcx;
            __builtin_amdgcn_global_load_lds((const AS1 void*)g, (AS3 void*)(As + cid * 512), 16, 0, 0);
        }
#pragma unroll
        for (int i = 0; i < 4; ++i) {
            int cid = wave * 4 + i;
            const ushort* g = we + (size_t)(n0 + cid * 8 + lr) * Dd + kb + lcx;
            __builtin_amdgcn_global_load_lds((const AS1 void*)g, (AS3 void*)(Bs + cid * 512), 16, 0, 0);
        }
        __syncthreads();
#pragma unroll
        for (int ks = 0; ks < 2; ++ks) {
            int px = ((ks * 4 + quad) ^ (col15 & 7)) * 8;   // swizzled k-offset (shorts)
            short8 a[4], b2[4];
#pragma unroll
            for (int mi = 0; mi < 4; ++mi)
                a[mi] = *(const short8*)&As[(wm + mi * 16 + col15) * 64 + px];
#pragma unroll
            for (int ni = 0; ni < 4; ++ni)
                b2[ni] = *(const short8*)&Bs[(wn + ni * 16 + col15) * 64 + px];
#pragma unroll
            for (int mi = 0; mi < 4; ++mi)
#pragma unroll
                for (int ni = 0; ni < 4; ++ni)
                    acc[mi][ni] = __builtin_amdgcn_mfma_f32_16x16x32_bf16(a[mi], b2[ni], acc[mi][ni], 0, 0, 0);
        }
        __syncthreads();
    }

    int oe = off[e];
    int hbase = (n0 + wn) >> 1;         // cols ni={0,1} -> h block 0, ni={2,3} -> h block 1
#pragma unroll
    for (int mi = 0; mi < 4; ++mi)
#pragma unroll
        for (int r = 0; r < 4; ++r) {
            int sl2 = m0 + wm + mi * 16 + quad * 4 + r;   // C layout: row = quad*4+reg
            if (sl2 < cn) {
                size_t rowb = (size_t)(oe + sl2) * Hh;
#pragma unroll
                for (int np = 0; np < 2; ++np) {
                    float h1 = acc[mi][np * 2][r], h3 = acc[mi][np * 2 + 1][r];
                    float s = h1 / (1.f + __expf(-h1));
                    Hbuf[rowb + hbase + np * 16 + col15] = f2bf(s * h3);
                }
            }
        }
}

// ---------- stage2: Yc[slot] = Hrow @ W2, tile 128x128, BK=64 ----------
// 1-D grid, 2304 blocks. XCD-pinned decode: xcd = b&7.
//   slot<256: routed e=xcd, x=slot>>2 (0..63), y=slot&3.
//   else: shared e=8, s=slot-256 (0..31), x=xcd*8+(s>>2), y=s&3.
__global__ __launch_bounds__(256, 3) void stage2_kernel(
        const ushort* __restrict__ Hbuf, const ushort* __restrict__ w2t,
        const int* __restrict__ cntc, const int* __restrict__ off,
        ushort* __restrict__ Yc) {
    int b = blockIdx.x;
    int xcd = b & 7, slot = b >> 3;
    int e, xblk, yblk;
    if (slot < 256) { e = xcd; xblk = slot >> 2; yblk = slot & 3; }
    else { int s = slot - 256; e = 8; xblk = (xcd << 3) + (s >> 2); yblk = s & 3; }
    int cn = cntc[e];
    int m0 = xblk * 128;
    if (m0 >= cn) return;
    int n0 = yblk * 128;
    int oe = off[e];
    const ushort* w2e = w2t + (size_t)e * Dd * Hh;

    __shared__ ushort As[128 * 64];
    __shared__ ushort Bs[128 * 64];

    int tid = threadIdx.x;
    int lane = tid & 63, wave = tid >> 6;
    int wm = (wave & 1) * 64, wn = (wave >> 1) * 64;
    int col15 = lane & 15, quad = lane >> 4;
    int lr = lane >> 3;
    int lcx = ((lane & 7) ^ lr) * 8;

    f32x4 acc[4][4];
#pragma unroll
    for (int a = 0; a < 4; ++a)
#pragma unroll
        for (int b2 = 0; b2 < 4; ++b2) acc[a][b2] = (f32x4){0.f, 0.f, 0.f, 0.f};

    for (int kb = 0; kb < Hh; kb += 64) {
#pragma unroll
        for (int i = 0; i < 4; ++i) {
            int cid = wave * 4 + i;
            const ushort* g = Hbuf + (size_t)(oe + m0 + cid * 8 + lr) * Hh + kb + lcx;
            __builtin_amdgcn_global_load_lds((const AS1 void*)g, (AS3 void*)(As + cid * 512), 16, 0, 0);
        }
#pragma unroll
        for (int i = 0; i < 4; ++i) {
            int cid = wave * 4 + i;
            const ushort* g = w2e + (size_t)(n0 + cid * 8 + lr) * Hh + kb + lcx;
            __builtin_amdgcn_global_load_lds((const AS1 void*)g, (AS3 void*)(Bs + cid * 512), 16, 0, 0);
        }
        __syncthreads();
#pragma unroll
        for (int ks = 0; ks < 2; ++ks) {
            int px = ((ks * 4 + quad) ^ (col15 & 7)) * 8;
            short8 a[4], b2[4];
#pragma unroll
            for (int mi = 0; mi < 4; ++mi)
                a[mi] = *(const short8*)&As[(wm + mi * 16 + col15) * 64 + px];
#pragma unroll
            for (int ni = 0; ni < 4; ++ni)
                b2[ni] = *(const short8*)&Bs[(wn + ni * 16 + col15) * 64 + px];
#pragma unroll
            for (int mi = 0; mi < 4; ++mi)
#pragma unroll
                for (int ni = 0; ni < 4; ++ni)
                    acc[mi][ni] = __builtin_amdgcn_mfma_f32_16x16x32_bf16(a[mi], b2[ni], acc[mi][ni], 0, 0, 0);
        }
        __syncthreads();
    }

#pragma unroll
    for (int mi = 0; mi < 4; ++mi)
#pragma unroll
        for (int r = 0; r < 4; ++r) {
            int sl2 = m0 + wm + mi * 16 + quad * 4 + r;
            if (sl2 < cn) {
                size_t rowb = (size_t)(oe + sl2) * Dd;
#pragma unroll
                for (int ni = 0; ni < 4; ++ni)
                    Yc[rowb + n0 + wn + ni * 16 + col15] = f2bf(acc[mi][ni][r]);
            }
        }
}

// ---------- combine: out[t] = g0*Yc[s0] + g1*Yc[s1] + Yc[shared+t] ----------
__global__ __launch_bounds__(256) void combine_kernel(const ushort* __restrict__ Yc,
        const int* __restrict__ slotp, const float* __restrict__ pg,
        const int* __restrict__ off, float* __restrict__ out) {
    int g = blockIdx.x * 256 + threadIdx.x;
    int t = g >> 6;
    int c = (g & 63) * 8;
    int p0 = slotp[t * 2], p1 = slotp[t * 2 + 1];
    float g0 = pg[t * 2], g1 = pg[t * 2 + 1];
    int s0 = off[p0 >> 16] + (p0 & 0xffff);
    int s1 = off[p1 >> 16] + (p1 & 0xffff);
    int s2 = off[8] + t;
    short8 a = *(const short8*)(Yc + (size_t)s0 * Dd + c);
    short8 b = *(const short8*)(Yc + (size_t)s1 * Dd + c);
    short8 d = *(const short8*)(Yc + (size_t)s2 * Dd + c);
    float o[8];
#pragma unroll
    for (int i = 0; i < 8; ++i)
        o[i] = g0 * bf2f(a[i]) + g1 * bf2f(b[i]) + bf2f(d[i]);
    float* dst = out + (size_t)t * Dd + c;
    *(float4*)dst = (float4){o[0], o[1], o[2], o[3]};
    *(float4*)(dst + 4) = (float4){o[4], o[5], o[6], o[7]};
}

extern "C" void kernel_launch(void* const* d_in, const int* in_sizes, int n_in,
                              void* d_out, int out_size, void* d_ws, size_t ws_size,
                              hipStream_t stream) {
    (void)in_sizes; (void)n_in; (void)out_size; (void)ws_size;
    const float* x    = (const float*)d_in[0];
    const float* gw   = (const float*)d_in[1];
    const float* bias = (const float*)d_in[2];
    const float* w1   = (const float*)d_in[3];
    const float* w3   = (const float*)d_in[4];
    const float* w2   = (const float*)d_in[5];
    const float* sw1  = (const float*)d_in[6];
    const float* sw3  = (const float*)d_in[7];
    const float* sw2  = (const float*)d_in[8];
    float* out = (float*)d_out;

    char* ws = (char*)d_ws;
    ushort* xb    = (ushort*)(ws + OFF_XB);
    ushort* w13t  = (ushort*)(ws + OFF_W13T);
    ushort* w2t   = (ushort*)(ws + OFF_W2T);
    ushort* Hbuf  = (ushort*)(ws + OFF_HBUF);
    ushort* Yc    = (ushort*)(ws + OFF_YC);
    int*    tok   = (int*)(ws + OFF_TOK);
    int*    slotp = (int*)(ws + OFF_SLOTP);
    float*  pg    = (float*)(ws + OFF_PG);
    int*    cnt   = (int*)(ws + OFF_CNT);
    int*    off   = (int*)(ws + OFF_OFFS);
    int*    cntc  = off + 16;

    hipMemsetAsync(cnt, 0, 1024, stream);

    trans_kernel<<<dim3(32, 16, 27), 256, 0, stream>>>(w1, sw1, w3, sw3, w2, sw2, w13t, w2t);
    router_kernel<<<256, 256, 0, stream>>>(x, gw, bias, cnt, tok, slotp, pg, xb);
    scan_kernel<<<1, 64, 0, stream>>>(cnt, off, cntc);

    stage1_kernel<<<9216, 256, 0, stream>>>(xb, w13t, tok, cntc, off, Hbuf);
    stage2_kernel<<<2304, 256, 0, stream>>>(Hbuf, w2t, cntc, off, Yc);
    combine_kernel<<<2048, 256, 0, stream>>>(Yc, slotp, pg, off, out);
}